// Round 1
// baseline (685.852 us; speedup 1.0000x reference)
//
#include <hip/hip_runtime.h>
#include <stdint.h>

// GCN 2-layer: h1 = relu(Anorm @ (x@W1) + b1); out = Anorm @ (h1@W2) + b2
// N=16384 nodes, K(features)=16384, C=256 hidden, 16 classes, E=524288 edges.
// Strategy: big GEMM in bf16 MFMA (fp32->bf16 fused into LDS staging),
// aggregation via CSR-by-dst gather (built on device each call).

namespace {
constexpr int NN = 16384;     // nodes
constexpr int CH = 256;       // hidden channels
constexpr int KC = 16;        // classes
constexpr int NE = 524288;    // edges
constexpr int KD = 16384;     // input feature dim

// workspace byte offsets (all 256-aligned)
constexpr size_t OFF_W1T  = 0;          // bf16 [256][16384]  = 8 MiB
constexpr size_t OFF_H    = 8388608;    // f32  [16384][256]  = 16 MiB
constexpr size_t OFF_OUT1 = 25165824;   // f32  [16384][256]  = 16 MiB
constexpr size_t OFF_H2   = 41943040;   // f32  [16384][16]   = 1 MiB
constexpr size_t OFF_DEG  = 42991616;   // f32  [16384]
constexpr size_t OFF_CNT  = 43057152;   // i32  [16384]   (contiguous w/ DEG for one memset)
constexpr size_t OFF_DINV = 43122688;   // f32  [16384]
constexpr size_t OFF_ROWP = 43188224;   // i32  [16385] (+pad)
constexpr size_t OFF_CUR  = 43254016;   // i32  [16384]
constexpr size_t OFF_COLS = 43319552;   // i32  [E] = 2 MiB
constexpr size_t OFF_NRM  = 45416704;   // f32  [E] = 2 MiB   (end ~45.3 MiB)
}

typedef __attribute__((ext_vector_type(8))) short bf16x8;
typedef __attribute__((ext_vector_type(4))) float f32x4;

__device__ __forceinline__ unsigned short f2bf(float f) {
  // round-to-nearest-even fp32 -> bf16 (inputs are finite)
  unsigned int u = __builtin_bit_cast(unsigned int, f);
  u += 0x7fffu + ((u >> 16) & 1u);
  return (unsigned short)(u >> 16);
}

// ---- W1 [16384][256] f32  ->  W1T [256][16384] bf16 ----
__global__ __launch_bounds__(256)
void k_w1t(const float* __restrict__ w1, unsigned short* __restrict__ w1t) {
  __shared__ float tile[64][65];
  const int t = threadIdx.x;
  const int kb = blockIdx.x * 64;   // rows of W1 (k)
  const int nb = blockIdx.y * 64;   // cols of W1 (n)
  const int r = t >> 6;             // 0..3
  const int c = t & 63;
#pragma unroll
  for (int i = 0; i < 16; ++i)
    tile[i * 4 + r][c] = w1[(size_t)(kb + i * 4 + r) * CH + nb + c];
  __syncthreads();
#pragma unroll
  for (int i = 0; i < 16; ++i)
    w1t[(size_t)(nb + i * 4 + r) * KD + kb + c] = f2bf(tile[c][i * 4 + r]);
}

// ---- degree + in-edge histogram ----
__global__ __launch_bounds__(256)
void k_deg(const int* __restrict__ dst, const float* __restrict__ ew,
           float* __restrict__ deg, int* __restrict__ cnt) {
  const int e = blockIdx.x * 256 + threadIdx.x;
  const int d = dst[e];
  atomicAdd(&deg[d], ew[e]);
  atomicAdd(&cnt[d], 1);
}

__global__ __launch_bounds__(256)
void k_dinv(const float* __restrict__ deg, float* __restrict__ dinv) {
  const int i = blockIdx.x * 256 + threadIdx.x;
  dinv[i] = rsqrtf(deg[i] + 1.0f);   // +1 = self-loop weight; deg >= 1 always
}

// ---- exclusive scan of cnt[16384] -> rowp, cursor (single block) ----
__global__ __launch_bounds__(256)
void k_scan(const int* __restrict__ cnt, int* __restrict__ rowp, int* __restrict__ curs) {
  __shared__ int ps[256];
  const int t = threadIdx.x;
  const int base = t * 64;
  int s = 0;
  for (int j = 0; j < 64; ++j) s += cnt[base + j];
  ps[t] = s;
  __syncthreads();
  int v = s;
  for (int off = 1; off < 256; off <<= 1) {
    int u = (t >= off) ? ps[t - off] : 0;
    __syncthreads();
    v += u;
    ps[t] = v;
    __syncthreads();
  }
  int run = v - s;   // exclusive prefix
  for (int j = 0; j < 64; ++j) {
    int c = cnt[base + j];
    rowp[base + j] = run;
    curs[base + j] = run;
    run += c;
  }
  if (t == 255) rowp[NN] = run;
}

// ---- CSR fill: edge -> (src, norm) bucketed by dst ----
__global__ __launch_bounds__(256)
void k_fill(const int* __restrict__ src, const int* __restrict__ dst,
            const float* __restrict__ ew, const float* __restrict__ dinv,
            int* __restrict__ curs, int* __restrict__ cols, float* __restrict__ nrm) {
  const int e = blockIdx.x * 256 + threadIdx.x;
  const int s = src[e], d = dst[e];
  const int pos = atomicAdd(&curs[d], 1);
  cols[pos] = s;
  nrm[pos] = dinv[s] * ew[e] * dinv[d];
}

// ---- GEMM1: h[16384][256] = x[16384][16384] @ W1 (bf16 MFMA) ----
// BM=64 BN=256 BK=32, 256 blocks (1/CU), 4 waves x (64x64), double-buffered LDS,
// XOR chunk swizzle: chunk = (k>>3) ^ ((line>>1)&3)  (2-way max on b128 r/w).
__global__ __launch_bounds__(256)
void k_gemm1(const float* __restrict__ x, const unsigned short* __restrict__ w1t,
             float* __restrict__ h) {
  __shared__ __align__(16) unsigned short As[2][64 * 32];
  __shared__ __align__(16) unsigned short Bs[2][256 * 32];

  const int tid  = threadIdx.x;
  const int lane = tid & 63;
  const int wave = tid >> 6;
  const int bm0  = blockIdx.x * 64;
  const int wn0  = wave * 64;

  // staging coords: thread -> (row ar, k-chunk kq of 8)
  const int ar  = tid >> 2;
  const int kq  = tid & 3;
  const int acn = kq ^ ((ar >> 1) & 3);
  const int aoff = ar * 32 + acn * 8;

  // fragment-read coords
  const int fr = lane & 15, fg = lane >> 4;
  const int fch = fg ^ ((fr >> 1) & 3);
  const int fA = fr * 32 + fch * 8;
  const int fB = (wn0 + fr) * 32 + fch * 8;

  const float* xrow = x + (size_t)(bm0 + ar) * KD + kq * 8;
  const unsigned short* brow = w1t + (size_t)ar * KD + kq * 8;

  float4 a0v, a1v;
  bf16x8 bv0, bv1, bv2, bv3;

  f32x4 acc[4][4] = {};

  auto LOADG = [&](int t) {
    const float* ap = xrow + (size_t)t * 32;
    a0v = *reinterpret_cast<const float4*>(ap);
    a1v = *reinterpret_cast<const float4*>(ap + 4);
    const unsigned short* bp = brow + (size_t)t * 32;
    bv0 = *reinterpret_cast<const bf16x8*>(bp);
    bv1 = *reinterpret_cast<const bf16x8*>(bp + (size_t)64 * KD);
    bv2 = *reinterpret_cast<const bf16x8*>(bp + (size_t)128 * KD);
    bv3 = *reinterpret_cast<const bf16x8*>(bp + (size_t)192 * KD);
  };
  auto STORE = [&](int buf) {
    bf16x8 ap;
    ap[0] = (short)f2bf(a0v.x); ap[1] = (short)f2bf(a0v.y);
    ap[2] = (short)f2bf(a0v.z); ap[3] = (short)f2bf(a0v.w);
    ap[4] = (short)f2bf(a1v.x); ap[5] = (short)f2bf(a1v.y);
    ap[6] = (short)f2bf(a1v.z); ap[7] = (short)f2bf(a1v.w);
    *reinterpret_cast<bf16x8*>(&As[buf][aoff]) = ap;
    *reinterpret_cast<bf16x8*>(&Bs[buf][(0 * 64 + ar) * 32 + acn * 8]) = bv0;
    *reinterpret_cast<bf16x8*>(&Bs[buf][(1 * 64 + ar) * 32 + acn * 8]) = bv1;
    *reinterpret_cast<bf16x8*>(&Bs[buf][(2 * 64 + ar) * 32 + acn * 8]) = bv2;
    *reinterpret_cast<bf16x8*>(&Bs[buf][(3 * 64 + ar) * 32 + acn * 8]) = bv3;
  };

  LOADG(0);
  STORE(0);
  __syncthreads();
  int cur = 0;

  for (int t = 0; t < KD / 32; ++t) {
    if (t + 1 < KD / 32) LOADG(t + 1);   // issue next tile's loads early
    bf16x8 af[4], bfr[4];
#pragma unroll
    for (int mi = 0; mi < 4; ++mi)
      af[mi] = *reinterpret_cast<const bf16x8*>(&As[cur][fA + mi * 512]);
#pragma unroll
    for (int ni = 0; ni < 4; ++ni)
      bfr[ni] = *reinterpret_cast<const bf16x8*>(&Bs[cur][fB + ni * 512]);
#pragma unroll
    for (int mi = 0; mi < 4; ++mi)
#pragma unroll
      for (int ni = 0; ni < 4; ++ni)
        acc[mi][ni] = __builtin_amdgcn_mfma_f32_16x16x32_bf16(af[mi], bfr[ni], acc[mi][ni], 0, 0, 0);
    if (t + 1 < KD / 32) {
      STORE(cur ^ 1);      // compiler inserts vmcnt wait here, after MFMAs
      __syncthreads();
      cur ^= 1;
    }
  }

  // epilogue: C/D layout col=lane&15, row=(lane>>4)*4+reg
#pragma unroll
  for (int mi = 0; mi < 4; ++mi)
#pragma unroll
    for (int ni = 0; ni < 4; ++ni)
#pragma unroll
      for (int r = 0; r < 4; ++r) {
        const int m = bm0 + mi * 16 + fg * 4 + r;
        const int n = wn0 + ni * 16 + fr;
        h[(size_t)m * CH + n] = acc[mi][ni][r];
      }
}

// ---- aggregation 1 (+b1, relu): out1[i][c] = relu(b1 + dinv_i^2*h[i] + sum norm*h[s]) ----
__global__ __launch_bounds__(256)
void k_agg1(const float* __restrict__ h, const int* __restrict__ rowp,
            const int* __restrict__ cols, const float* __restrict__ nrm,
            const float* __restrict__ dinv, const float* __restrict__ b1,
            float* __restrict__ out1) {
  const int i = blockIdx.x;
  const int c = threadIdx.x;
  const int beg = rowp[i], end = rowp[i + 1];
  const float di = dinv[i];
  float acc = di * di * h[(size_t)i * CH + c];
  int e = beg;
  for (; e + 2 <= end; e += 2) {
    const int s0 = cols[e], s1 = cols[e + 1];
    const float n0 = nrm[e], n1 = nrm[e + 1];
    acc += n0 * h[(size_t)s0 * CH + c];
    acc += n1 * h[(size_t)s1 * CH + c];
  }
  if (e < end) acc += nrm[e] * h[(size_t)cols[e] * CH + c];
  out1[(size_t)i * CH + c] = fmaxf(acc + b1[c], 0.0f);
}

// ---- GEMM2: h2[16384][16] = out1 @ W2[256][16] ----
__global__ __launch_bounds__(256)
void k_gemm2(const float* __restrict__ out1, const float* __restrict__ w2,
             float* __restrict__ h2) {
  __shared__ float xs[16][256];
  __shared__ float ws[256 * 16];
  const int t = threadIdx.x;
  const int n0 = blockIdx.x * 16;
#pragma unroll
  for (int i = 0; i < 16; ++i) ws[i * 256 + t] = w2[i * 256 + t];
#pragma unroll
  for (int i = 0; i < 16; ++i) xs[i][t] = out1[(size_t)(n0 + i) * CH + t];
  __syncthreads();
  const int node = t >> 4, k = t & 15;
  float acc = 0.f;
#pragma unroll 8
  for (int c = 0; c < 256; ++c) acc += xs[node][c] * ws[c * 16 + k];
  h2[(size_t)(n0 + node) * KC + k] = acc;
}

// ---- aggregation 2 (+b2): one wave per node ----
__global__ __launch_bounds__(256)
void k_agg2(const float* __restrict__ h2, const int* __restrict__ rowp,
            const int* __restrict__ cols, const float* __restrict__ nrm,
            const float* __restrict__ dinv, const float* __restrict__ b2,
            float* __restrict__ out) {
  const int i = blockIdx.x * 4 + (threadIdx.x >> 6);
  const int lane = threadIdx.x & 63;
  const int k = lane & 15, g = lane >> 4;
  const int beg = rowp[i], end = rowp[i + 1];
  float acc = 0.f;
  for (int e = beg + g; e < end; e += 4)
    acc += nrm[e] * h2[(size_t)cols[e] * KC + k];
  acc += __shfl_xor(acc, 16);
  acc += __shfl_xor(acc, 32);
  if (g == 0) {
    const float di = dinv[i];
    out[(size_t)i * KC + k] = acc + di * di * h2[(size_t)i * KC + k] + b2[k];
  }
}

extern "C" void kernel_launch(void* const* d_in, const int* in_sizes, int n_in,
                              void* d_out, int out_size, void* d_ws, size_t ws_size,
                              hipStream_t stream) {
  const float* x  = (const float*)d_in[0];
  const int*   ei = (const int*)d_in[1];
  const float* ew = (const float*)d_in[2];
  const float* w1 = (const float*)d_in[3];
  const float* b1 = (const float*)d_in[4];
  const float* w2 = (const float*)d_in[5];
  const float* b2 = (const float*)d_in[6];
  const int* src = ei;
  const int* dst = ei + NE;

  uint8_t* ws = (uint8_t*)d_ws;
  unsigned short* w1t = (unsigned short*)(ws + OFF_W1T);
  float* h    = (float*)(ws + OFF_H);
  float* out1 = (float*)(ws + OFF_OUT1);
  float* h2   = (float*)(ws + OFF_H2);
  float* deg  = (float*)(ws + OFF_DEG);
  int*   cnt  = (int*)(ws + OFF_CNT);
  float* dinv = (float*)(ws + OFF_DINV);
  int*   rowp = (int*)(ws + OFF_ROWP);
  int*   curs = (int*)(ws + OFF_CUR);
  int*   cols = (int*)(ws + OFF_COLS);
  float* nrm  = (float*)(ws + OFF_NRM);
  float* out  = (float*)d_out;

  hipMemsetAsync(ws + OFF_DEG, 0, 131072, stream);  // deg + cnt

  k_w1t <<<dim3(256, 4), 256, 0, stream>>>(w1, w1t);
  k_deg <<<NE / 256, 256, 0, stream>>>(dst, ew, deg, cnt);
  k_dinv<<<NN / 256, 256, 0, stream>>>(deg, dinv);
  k_scan<<<1, 256, 0, stream>>>(cnt, rowp, curs);
  k_fill<<<NE / 256, 256, 0, stream>>>(src, dst, ew, dinv, curs, cols, nrm);
  k_gemm1<<<NN / 64, 256, 0, stream>>>(x, w1t, h);
  k_agg1<<<NN, 256, 0, stream>>>(h, rowp, cols, nrm, dinv, b1, out1);
  k_gemm2<<<NN / 16, 256, 0, stream>>>(out1, w2, h2);
  k_agg2<<<NN / 4, 256, 0, stream>>>(h2, rowp, cols, nrm, dinv, b2, out);
}

// Round 2
// 541.619 us; speedup vs baseline: 1.2663x; 1.2663x over previous
//
#include <hip/hip_runtime.h>
#include <stdint.h>

// GCN 2-layer: h1 = relu(Anorm @ (x@W1) + b1); out = Anorm @ (h1@W2) + b2
// N=16384 nodes, K(features)=16384, C=256 hidden, 16 classes, E=524288 edges.
// R2: GEMM1 K-split x2 (2 blocks/CU -> barrier drains overlap across blocks);
//     h stored bf16 (agg1 gather traffic halved).

namespace {
constexpr int NN = 16384;     // nodes
constexpr int CH = 256;       // hidden channels
constexpr int KC = 16;        // classes
constexpr int NE = 524288;    // edges
constexpr int KD = 16384;     // input feature dim
constexpr int KSPLIT = 2;

// workspace byte offsets
constexpr size_t OFF_W1T  = 0;          // bf16 [256][16384]      = 8 MiB
constexpr size_t OFF_HP   = 8388608;    // f32  [2][16384][256]   = 32 MiB
constexpr size_t OFF_HB   = 41943040;   // bf16 [16384][256]      = 8 MiB
constexpr size_t OFF_OUT1 = 50331648;   // f32  [16384][256]      = 16 MiB
constexpr size_t OFF_H2   = 67108864;   // f32  [16384][16]       = 1 MiB
constexpr size_t OFF_DEG  = 71303168;   // f32  [16384]
constexpr size_t OFF_CNT  = 71368704;   // i32  [16384]  (contiguous w/ DEG: one memset)
constexpr size_t OFF_DINV = 71434240;   // f32  [16384]
constexpr size_t OFF_ROWP = 71499776;   // i32  [16385]
constexpr size_t OFF_CUR  = 71630848;   // i32  [16384]
constexpr size_t OFF_COLS = 71761920;   // i32  [E] = 2 MiB
constexpr size_t OFF_NRM  = 73859072;   // f32  [E] = 2 MiB
}

typedef __attribute__((ext_vector_type(8))) short bf16x8;
typedef __attribute__((ext_vector_type(4))) float f32x4;

__device__ __forceinline__ unsigned short f2bf(float f) {
  unsigned int u = __builtin_bit_cast(unsigned int, f);
  u += 0x7fffu + ((u >> 16) & 1u);
  return (unsigned short)(u >> 16);
}
__device__ __forceinline__ float bf2f(unsigned short v) {
  unsigned int u = ((unsigned int)v) << 16;
  return __builtin_bit_cast(float, u);
}

// ---- W1 [16384][256] f32  ->  W1T [256][16384] bf16 ----
__global__ __launch_bounds__(256)
void k_w1t(const float* __restrict__ w1, unsigned short* __restrict__ w1t) {
  __shared__ float tile[64][65];
  const int t = threadIdx.x;
  const int kb = blockIdx.x * 64;
  const int nb = blockIdx.y * 64;
  const int r = t >> 6;
  const int c = t & 63;
#pragma unroll
  for (int i = 0; i < 16; ++i)
    tile[i * 4 + r][c] = w1[(size_t)(kb + i * 4 + r) * CH + nb + c];
  __syncthreads();
#pragma unroll
  for (int i = 0; i < 16; ++i)
    w1t[(size_t)(nb + i * 4 + r) * KD + kb + c] = f2bf(tile[c][i * 4 + r]);
}

// ---- degree + in-edge histogram ----
__global__ __launch_bounds__(256)
void k_deg(const int* __restrict__ dst, const float* __restrict__ ew,
           float* __restrict__ deg, int* __restrict__ cnt) {
  const int e = blockIdx.x * 256 + threadIdx.x;
  const int d = dst[e];
  atomicAdd(&deg[d], ew[e]);
  atomicAdd(&cnt[d], 1);
}

__global__ __launch_bounds__(256)
void k_dinv(const float* __restrict__ deg, float* __restrict__ dinv) {
  const int i = blockIdx.x * 256 + threadIdx.x;
  dinv[i] = rsqrtf(deg[i] + 1.0f);   // +1 = self-loop weight
}

// ---- exclusive scan of cnt[16384] -> rowp, cursor (single block) ----
__global__ __launch_bounds__(256)
void k_scan(const int* __restrict__ cnt, int* __restrict__ rowp, int* __restrict__ curs) {
  __shared__ int ps[256];
  const int t = threadIdx.x;
  const int base = t * 64;
  int s = 0;
  for (int j = 0; j < 64; ++j) s += cnt[base + j];
  ps[t] = s;
  __syncthreads();
  int v = s;
  for (int off = 1; off < 256; off <<= 1) {
    int u = (t >= off) ? ps[t - off] : 0;
    __syncthreads();
    v += u;
    ps[t] = v;
    __syncthreads();
  }
  int run = v - s;
  for (int j = 0; j < 64; ++j) {
    int c = cnt[base + j];
    rowp[base + j] = run;
    curs[base + j] = run;
    run += c;
  }
  if (t == 255) rowp[NN] = run;
}

// ---- CSR fill: edge -> (src, norm) bucketed by dst ----
__global__ __launch_bounds__(256)
void k_fill(const int* __restrict__ src, const int* __restrict__ dst,
            const float* __restrict__ ew, const float* __restrict__ dinv,
            int* __restrict__ curs, int* __restrict__ cols, float* __restrict__ nrm) {
  const int e = blockIdx.x * 256 + threadIdx.x;
  const int s = src[e], d = dst[e];
  const int pos = atomicAdd(&curs[d], 1);
  cols[pos] = s;
  nrm[pos] = dinv[s] * ew[e] * dinv[d];
}

// ---- GEMM1: hp[kb][16384][256] = x[:, kb-half] @ W1T[kb-half] (bf16 MFMA) ----
// BM=64 BN=256 BK=32, KSPLIT=2 -> grid 512 (2 blocks/CU), 4 waves x (64x64).
__global__ __launch_bounds__(256)
void k_gemm1(const float* __restrict__ x, const unsigned short* __restrict__ w1t,
             float* __restrict__ hp) {
  __shared__ __align__(16) unsigned short As[2][64 * 32];
  __shared__ __align__(16) unsigned short Bs[2][256 * 32];

  const int tid  = threadIdx.x;
  const int lane = tid & 63;
  const int wave = tid >> 6;
  const int bm0  = (blockIdx.x >> 1) * 64;
  const int kb   = blockIdx.x & 1;
  const int koff = kb * (KD / KSPLIT);
  const int wn0  = wave * 64;

  const int ar  = tid >> 2;
  const int kq  = tid & 3;
  const int acn = kq ^ ((ar >> 1) & 3);
  const int aoff = ar * 32 + acn * 8;

  const int fr = lane & 15, fg = lane >> 4;
  const int fch = fg ^ ((fr >> 1) & 3);
  const int fA = fr * 32 + fch * 8;
  const int fB = (wn0 + fr) * 32 + fch * 8;

  const float* xrow = x + (size_t)(bm0 + ar) * KD + koff + kq * 8;
  const unsigned short* brow = w1t + (size_t)ar * KD + koff + kq * 8;

  float4 a0v, a1v;
  bf16x8 bv0, bv1, bv2, bv3;
  f32x4 acc[4][4] = {};

  auto LOADG = [&](int t) {
    const float* ap = xrow + (size_t)t * 32;
    a0v = *reinterpret_cast<const float4*>(ap);
    a1v = *reinterpret_cast<const float4*>(ap + 4);
    const unsigned short* bp = brow + (size_t)t * 32;
    bv0 = *reinterpret_cast<const bf16x8*>(bp);
    bv1 = *reinterpret_cast<const bf16x8*>(bp + (size_t)64 * KD);
    bv2 = *reinterpret_cast<const bf16x8*>(bp + (size_t)128 * KD);
    bv3 = *reinterpret_cast<const bf16x8*>(bp + (size_t)192 * KD);
  };
  auto STORE = [&](int buf) {
    bf16x8 ap;
    ap[0] = (short)f2bf(a0v.x); ap[1] = (short)f2bf(a0v.y);
    ap[2] = (short)f2bf(a0v.z); ap[3] = (short)f2bf(a0v.w);
    ap[4] = (short)f2bf(a1v.x); ap[5] = (short)f2bf(a1v.y);
    ap[6] = (short)f2bf(a1v.z); ap[7] = (short)f2bf(a1v.w);
    *reinterpret_cast<bf16x8*>(&As[buf][aoff]) = ap;
    *reinterpret_cast<bf16x8*>(&Bs[buf][(0 * 64 + ar) * 32 + acn * 8]) = bv0;
    *reinterpret_cast<bf16x8*>(&Bs[buf][(1 * 64 + ar) * 32 + acn * 8]) = bv1;
    *reinterpret_cast<bf16x8*>(&Bs[buf][(2 * 64 + ar) * 32 + acn * 8]) = bv2;
    *reinterpret_cast<bf16x8*>(&Bs[buf][(3 * 64 + ar) * 32 + acn * 8]) = bv3;
  };

  constexpr int NT = KD / KSPLIT / 32;   // 256
  LOADG(0);
  STORE(0);
  __syncthreads();
  int cur = 0;

  for (int t = 0; t < NT; ++t) {
    if (t + 1 < NT) LOADG(t + 1);
    bf16x8 af[4], bfr[4];
#pragma unroll
    for (int mi = 0; mi < 4; ++mi)
      af[mi] = *reinterpret_cast<const bf16x8*>(&As[cur][fA + mi * 512]);
#pragma unroll
    for (int ni = 0; ni < 4; ++ni)
      bfr[ni] = *reinterpret_cast<const bf16x8*>(&Bs[cur][fB + ni * 512]);
#pragma unroll
    for (int mi = 0; mi < 4; ++mi)
#pragma unroll
      for (int ni = 0; ni < 4; ++ni)
        acc[mi][ni] = __builtin_amdgcn_mfma_f32_16x16x32_bf16(af[mi], bfr[ni], acc[mi][ni], 0, 0, 0);
    if (t + 1 < NT) {
      STORE(cur ^ 1);
      __syncthreads();
      cur ^= 1;
    }
  }

  float* hpo = hp + (size_t)kb * NN * CH;
#pragma unroll
  for (int mi = 0; mi < 4; ++mi)
#pragma unroll
    for (int ni = 0; ni < 4; ++ni)
#pragma unroll
      for (int r = 0; r < 4; ++r) {
        const int m = bm0 + mi * 16 + fg * 4 + r;
        const int n = wn0 + ni * 16 + fr;
        hpo[(size_t)m * CH + n] = acc[mi][ni][r];
      }
}

// ---- reduce partials -> h bf16 ----
__global__ __launch_bounds__(256)
void k_hred(const float* __restrict__ hp, unsigned short* __restrict__ hb) {
  const size_t i = ((size_t)blockIdx.x * 256 + threadIdx.x) * 8;
  const float4 a0 = *reinterpret_cast<const float4*>(hp + i);
  const float4 a1 = *reinterpret_cast<const float4*>(hp + i + 4);
  const float4 b0 = *reinterpret_cast<const float4*>(hp + (size_t)NN * CH + i);
  const float4 b1 = *reinterpret_cast<const float4*>(hp + (size_t)NN * CH + i + 4);
  bf16x8 o;
  o[0] = (short)f2bf(a0.x + b0.x); o[1] = (short)f2bf(a0.y + b0.y);
  o[2] = (short)f2bf(a0.z + b0.z); o[3] = (short)f2bf(a0.w + b0.w);
  o[4] = (short)f2bf(a1.x + b1.x); o[5] = (short)f2bf(a1.y + b1.y);
  o[6] = (short)f2bf(a1.z + b1.z); o[7] = (short)f2bf(a1.w + b1.w);
  *reinterpret_cast<bf16x8*>(hb + i) = o;
}

// ---- aggregation 1 (+b1, relu), bf16 h gathers ----
__global__ __launch_bounds__(256)
void k_agg1(const unsigned short* __restrict__ hb, const int* __restrict__ rowp,
            const int* __restrict__ cols, const float* __restrict__ nrm,
            const float* __restrict__ dinv, const float* __restrict__ b1,
            float* __restrict__ out1) {
  const int i = blockIdx.x;
  const int c = threadIdx.x;
  const int beg = rowp[i], end = rowp[i + 1];
  const float di = dinv[i];
  float acc = di * di * bf2f(hb[(size_t)i * CH + c]);
  int e = beg;
  for (; e + 2 <= end; e += 2) {
    const int s0 = cols[e], s1 = cols[e + 1];
    const float n0 = nrm[e], n1 = nrm[e + 1];
    acc += n0 * bf2f(hb[(size_t)s0 * CH + c]);
    acc += n1 * bf2f(hb[(size_t)s1 * CH + c]);
  }
  if (e < end) acc += nrm[e] * bf2f(hb[(size_t)cols[e] * CH + c]);
  out1[(size_t)i * CH + c] = fmaxf(acc + b1[c], 0.0f);
}

// ---- GEMM2: h2[16384][16] = out1 @ W2[256][16] ----
__global__ __launch_bounds__(256)
void k_gemm2(const float* __restrict__ out1, const float* __restrict__ w2,
             float* __restrict__ h2) {
  __shared__ float xs[16][256];
  __shared__ float ws[256 * 16];
  const int t = threadIdx.x;
  const int n0 = blockIdx.x * 16;
#pragma unroll
  for (int i = 0; i < 16; ++i) ws[i * 256 + t] = w2[i * 256 + t];
#pragma unroll
  for (int i = 0; i < 16; ++i) xs[i][t] = out1[(size_t)(n0 + i) * CH + t];
  __syncthreads();
  const int node = t >> 4, k = t & 15;
  float acc = 0.f;
#pragma unroll 8
  for (int c = 0; c < 256; ++c) acc += xs[node][c] * ws[c * 16 + k];
  h2[(size_t)(n0 + node) * KC + k] = acc;
}

// ---- aggregation 2 (+b2): one wave per node ----
__global__ __launch_bounds__(256)
void k_agg2(const float* __restrict__ h2, const int* __restrict__ rowp,
            const int* __restrict__ cols, const float* __restrict__ nrm,
            const float* __restrict__ dinv, const float* __restrict__ b2,
            float* __restrict__ out) {
  const int i = blockIdx.x * 4 + (threadIdx.x >> 6);
  const int lane = threadIdx.x & 63;
  const int k = lane & 15, g = lane >> 4;
  const int beg = rowp[i], end = rowp[i + 1];
  float acc = 0.f;
  for (int e = beg + g; e < end; e += 4)
    acc += nrm[e] * h2[(size_t)cols[e] * KC + k];
  acc += __shfl_xor(acc, 16);
  acc += __shfl_xor(acc, 32);
  if (g == 0) {
    const float di = dinv[i];
    out[(size_t)i * KC + k] = acc + di * di * h2[(size_t)i * KC + k] + b2[k];
  }
}

extern "C" void kernel_launch(void* const* d_in, const int* in_sizes, int n_in,
                              void* d_out, int out_size, void* d_ws, size_t ws_size,
                              hipStream_t stream) {
  const float* x  = (const float*)d_in[0];
  const int*   ei = (const int*)d_in[1];
  const float* ew = (const float*)d_in[2];
  const float* w1 = (const float*)d_in[3];
  const float* b1 = (const float*)d_in[4];
  const float* w2 = (const float*)d_in[5];
  const float* b2 = (const float*)d_in[6];
  const int* src = ei;
  const int* dst = ei + NE;

  uint8_t* ws = (uint8_t*)d_ws;
  unsigned short* w1t = (unsigned short*)(ws + OFF_W1T);
  float* hp   = (float*)(ws + OFF_HP);
  unsigned short* hb = (unsigned short*)(ws + OFF_HB);
  float* out1 = (float*)(ws + OFF_OUT1);
  float* h2   = (float*)(ws + OFF_H2);
  float* deg  = (float*)(ws + OFF_DEG);
  int*   cnt  = (int*)(ws + OFF_CNT);
  float* dinv = (float*)(ws + OFF_DINV);
  int*   rowp = (int*)(ws + OFF_ROWP);
  int*   curs = (int*)(ws + OFF_CUR);
  int*   cols = (int*)(ws + OFF_COLS);
  float* nrm  = (float*)(ws + OFF_NRM);
  float* out  = (float*)d_out;

  hipMemsetAsync(ws + OFF_DEG, 0, 131072, stream);  // deg + cnt

  k_w1t <<<dim3(256, 4), 256, 0, stream>>>(w1, w1t);
  k_deg <<<NE / 256, 256, 0, stream>>>(dst, ew, deg, cnt);
  k_dinv<<<NN / 256, 256, 0, stream>>>(deg, dinv);
  k_scan<<<1, 256, 0, stream>>>(cnt, rowp, curs);
  k_fill<<<NE / 256, 256, 0, stream>>>(src, dst, ew, dinv, curs, cols, nrm);
  k_gemm1<<<(NN / 64) * KSPLIT, 256, 0, stream>>>(x, w1t, hp);
  k_hred<<<NN * CH / (256 * 8), 256, 0, stream>>>(hp, hb);
  k_agg1<<<NN, 256, 0, stream>>>(hb, rowp, cols, nrm, dinv, b1, out1);
  k_gemm2<<<NN / 16, 256, 0, stream>>>(out1, w2, h2);
  k_agg2<<<NN / 4, 256, 0, stream>>>(h2, rowp, cols, nrm, dinv, b2, out);
}

// Round 3
// 484.289 us; speedup vs baseline: 1.4162x; 1.1184x over previous
//
#include <hip/hip_runtime.h>
#include <stdint.h>

// GCN 2-layer: h1 = relu(Anorm @ (x@W1) + b1); out = Anorm @ (h1@W2) + b2
// R3: GEMM1 BM=128 KSPLIT=4 (B cache volume halved), XCD-grouped kb (B panel
//     L2-resident per XCD), B staged via global_load_lds w/ pre-swizzled src,
//     agg1 edge lists staged in LDS.

namespace {
constexpr int NN = 16384;     // nodes
constexpr int CH = 256;       // hidden channels
constexpr int KC = 16;        // classes
constexpr int NE = 524288;    // edges
constexpr int KD = 16384;     // input feature dim
constexpr int KSPLIT = 4;
constexpr int BM = 128;

// workspace byte offsets
constexpr size_t OFF_W1T  = 0;            // bf16 [256][16384]        = 8 MiB
constexpr size_t OFF_HP   = 8388608;      // f32  [4][16384][256]     = 64 MiB
constexpr size_t OFF_HB   = 75497472;     // bf16 [16384][256]        = 8 MiB
constexpr size_t OFF_OUT1 = 83886080;     // f32  [16384][256]        = 16 MiB
constexpr size_t OFF_H2   = 100663296;    // f32  [16384][16]         = 1 MiB
constexpr size_t OFF_DEG  = 101711872;    // f32  [16384]
constexpr size_t OFF_CNT  = 101777408;    // i32  [16384] (contiguous w/ DEG)
constexpr size_t OFF_DINV = 101842944;    // f32  [16384]
constexpr size_t OFF_ROWP = 101908480;    // i32  [16385]
constexpr size_t OFF_CUR  = 102039552;    // i32  [16384]
constexpr size_t OFF_COLS = 102105088;    // i32  [E] = 2 MiB
constexpr size_t OFF_NRM  = 104202240;    // f32  [E] = 2 MiB
}

typedef __attribute__((ext_vector_type(8))) short bf16x8;
typedef __attribute__((ext_vector_type(4))) float f32x4;

__device__ __forceinline__ unsigned short f2bf(float f) {
  unsigned int u = __builtin_bit_cast(unsigned int, f);
  u += 0x7fffu + ((u >> 16) & 1u);
  return (unsigned short)(u >> 16);
}
__device__ __forceinline__ float bf2f(unsigned short v) {
  unsigned int u = ((unsigned int)v) << 16;
  return __builtin_bit_cast(float, u);
}

// ---- W1 [16384][256] f32  ->  W1T [256][16384] bf16 ----
__global__ __launch_bounds__(256)
void k_w1t(const float* __restrict__ w1, unsigned short* __restrict__ w1t) {
  __shared__ float tile[64][65];
  const int t = threadIdx.x;
  const int kb = blockIdx.x * 64;
  const int nb = blockIdx.y * 64;
  const int r = t >> 6;
  const int c = t & 63;
#pragma unroll
  for (int i = 0; i < 16; ++i)
    tile[i * 4 + r][c] = w1[(size_t)(kb + i * 4 + r) * CH + nb + c];
  __syncthreads();
#pragma unroll
  for (int i = 0; i < 16; ++i)
    w1t[(size_t)(nb + i * 4 + r) * KD + kb + c] = f2bf(tile[c][i * 4 + r]);
}

// ---- degree + in-edge histogram ----
__global__ __launch_bounds__(256)
void k_deg(const int* __restrict__ dst, const float* __restrict__ ew,
           float* __restrict__ deg, int* __restrict__ cnt) {
  const int e = blockIdx.x * 256 + threadIdx.x;
  const int d = dst[e];
  atomicAdd(&deg[d], ew[e]);
  atomicAdd(&cnt[d], 1);
}

__global__ __launch_bounds__(256)
void k_dinv(const float* __restrict__ deg, float* __restrict__ dinv) {
  const int i = blockIdx.x * 256 + threadIdx.x;
  dinv[i] = rsqrtf(deg[i] + 1.0f);   // +1 = self-loop weight
}

// ---- exclusive scan of cnt[16384] -> rowp, cursor (single block) ----
__global__ __launch_bounds__(256)
void k_scan(const int* __restrict__ cnt, int* __restrict__ rowp, int* __restrict__ curs) {
  __shared__ int ps[256];
  const int t = threadIdx.x;
  const int base = t * 64;
  int s = 0;
  for (int j = 0; j < 64; ++j) s += cnt[base + j];
  ps[t] = s;
  __syncthreads();
  int v = s;
  for (int off = 1; off < 256; off <<= 1) {
    int u = (t >= off) ? ps[t - off] : 0;
    __syncthreads();
    v += u;
    ps[t] = v;
    __syncthreads();
  }
  int run = v - s;
  for (int j = 0; j < 64; ++j) {
    int c = cnt[base + j];
    rowp[base + j] = run;
    curs[base + j] = run;
    run += c;
  }
  if (t == 255) rowp[NN] = run;
}

// ---- CSR fill: edge -> (src, norm) bucketed by dst ----
__global__ __launch_bounds__(256)
void k_fill(const int* __restrict__ src, const int* __restrict__ dst,
            const float* __restrict__ ew, const float* __restrict__ dinv,
            int* __restrict__ curs, int* __restrict__ cols, float* __restrict__ nrm) {
  const int e = blockIdx.x * 256 + threadIdx.x;
  const int s = src[e], d = dst[e];
  const int pos = atomicAdd(&curs[d], 1);
  cols[pos] = s;
  nrm[pos] = dinv[s] * ew[e] * dinv[d];
}

// ---- GEMM1: hp[kb][16384][256] = x[:, kb-quarter] @ W1T[kb-quarter] ----
// BM=128 BN=256 BK=32, KSPLIT=4 -> grid 512 (2 blocks/CU, 48 KB LDS each).
// kb grouped by XCD (bid&7)>>1 so each XCD streams ONE 2 MiB B panel (L2-fit).
__global__ __launch_bounds__(256)
void k_gemm1(const float* __restrict__ x, const unsigned short* __restrict__ w1t,
             float* __restrict__ hp) {
  __shared__ __align__(16) unsigned short As[2][BM * 32];    // 16 KB
  __shared__ __align__(16) unsigned short Bs[2][256 * 32];   // 32 KB

  const int tid  = threadIdx.x;
  const int lane = tid & 63;
  const int wave = tid >> 6;

  // XCD-grouped decode: hw round-robins blockIdx % 8 across XCDs
  const int bid  = blockIdx.x;
  const int xcd  = bid & 7;
  const int slot = bid >> 3;                   // 0..63
  const int kb   = xcd >> 1;                   // 0..3, constant per XCD
  const int bm0  = (slot * 2 + (xcd & 1)) * BM;
  const int koff = kb * (KD / KSPLIT);         // 4096-col quarter
  const int wn0  = wave * 64;

  // A staging: thread -> rows r0, r0+64, k-chunk kq (8 floats), XOR chunk swz
  const int r0  = tid >> 2;
  const int kq  = tid & 3;
  const int acn = kq ^ ((r0 >> 1) & 3);        // ((r0+64)>>1)&3 == (r0>>1)&3
  const int aoff0 = r0 * 32 + acn * 8;
  const int aoff1 = (r0 + 64) * 32 + acn * 8;

  // B async staging: per wave 4x global_load_lds(16B); linear LDS dest,
  // pre-swizzled global source (content at row r chunk j = global j^((r>>1)&3))
  const int cc = (lane & 3) ^ ((lane >> 3) & 3);
  const unsigned short* bbase =
      w1t + (size_t)(wave * 64 + (lane >> 2)) * KD + koff + cc * 8;

  // fragment-read coords
  const int fr = lane & 15, fg = lane >> 4;
  const int fch = fg ^ ((fr >> 1) & 3);
  const int fA = fr * 32 + fch * 8;
  const int fB = (wn0 + fr) * 32 + fch * 8;

  const float* xrow0 = x + (size_t)(bm0 + r0) * KD + koff + kq * 8;
  const float* xrow1 = xrow0 + (size_t)64 * KD;

  float4 a00, a01, a10, a11;
  f32x4 acc[8][4] = {};

  auto GLOADB = [&](int t, int buf) {
    const unsigned short* g = bbase + (size_t)t * 32;
#pragma unroll
    for (int i = 0; i < 4; ++i) {
      __builtin_amdgcn_global_load_lds(
          (const __attribute__((address_space(1))) void*)(g + (size_t)i * 16 * KD),
          (__attribute__((address_space(3))) void*)(&Bs[buf][(wave * 64 + i * 16) * 32]),
          16, 0, 0);
    }
  };
  auto LOADA = [&](int t) {
    const float* p0 = xrow0 + (size_t)t * 32;
    const float* p1 = xrow1 + (size_t)t * 32;
    a00 = *reinterpret_cast<const float4*>(p0);
    a01 = *reinterpret_cast<const float4*>(p0 + 4);
    a10 = *reinterpret_cast<const float4*>(p1);
    a11 = *reinterpret_cast<const float4*>(p1 + 4);
  };
  auto STOREA = [&](int buf) {
    bf16x8 v;
    v[0] = (short)f2bf(a00.x); v[1] = (short)f2bf(a00.y);
    v[2] = (short)f2bf(a00.z); v[3] = (short)f2bf(a00.w);
    v[4] = (short)f2bf(a01.x); v[5] = (short)f2bf(a01.y);
    v[6] = (short)f2bf(a01.z); v[7] = (short)f2bf(a01.w);
    *reinterpret_cast<bf16x8*>(&As[buf][aoff0]) = v;
    v[0] = (short)f2bf(a10.x); v[1] = (short)f2bf(a10.y);
    v[2] = (short)f2bf(a10.z); v[3] = (short)f2bf(a10.w);
    v[4] = (short)f2bf(a11.x); v[5] = (short)f2bf(a11.y);
    v[6] = (short)f2bf(a11.z); v[7] = (short)f2bf(a11.w);
    *reinterpret_cast<bf16x8*>(&As[buf][aoff1]) = v;
  };

  constexpr int NT = KD / KSPLIT / 32;   // 128
  GLOADB(0, 0);
  LOADA(0);
  STOREA(0);
  __syncthreads();
  int cur = 0;

  for (int t = 0; t < NT; ++t) {
    if (t + 1 < NT) {
      GLOADB(t + 1, cur ^ 1);   // async into the free buffer
      LOADA(t + 1);
    }
    bf16x8 bfr[4];
#pragma unroll
    for (int ni = 0; ni < 4; ++ni)
      bfr[ni] = *reinterpret_cast<const bf16x8*>(&Bs[cur][fB + ni * 512]);
#pragma unroll
    for (int mi = 0; mi < 8; ++mi) {
      const bf16x8 af = *reinterpret_cast<const bf16x8*>(&As[cur][fA + mi * 512]);
#pragma unroll
      for (int ni = 0; ni < 4; ++ni)
        acc[mi][ni] = __builtin_amdgcn_mfma_f32_16x16x32_bf16(af, bfr[ni], acc[mi][ni], 0, 0, 0);
    }
    if (t + 1 < NT) {
      STOREA(cur ^ 1);          // waits its own vmem; barrier drains the rest
      __syncthreads();
      cur ^= 1;
    }
  }

  float* hpo = hp + (size_t)kb * NN * CH;
#pragma unroll
  for (int mi = 0; mi < 8; ++mi)
#pragma unroll
    for (int ni = 0; ni < 4; ++ni)
#pragma unroll
      for (int r = 0; r < 4; ++r) {
        const int m = bm0 + mi * 16 + fg * 4 + r;
        const int n = wn0 + ni * 16 + fr;
        hpo[(size_t)m * CH + n] = acc[mi][ni][r];
      }
}

// ---- reduce 4 partials -> h bf16 ----
__global__ __launch_bounds__(256)
void k_hred(const float* __restrict__ hp, unsigned short* __restrict__ hb) {
  const size_t i = ((size_t)blockIdx.x * 256 + threadIdx.x) * 8;
  float s[8];
#pragma unroll
  for (int j = 0; j < 8; ++j) s[j] = 0.f;
#pragma unroll
  for (int p = 0; p < KSPLIT; ++p) {
    const float* q = hp + (size_t)p * NN * CH + i;
    const float4 v0 = *reinterpret_cast<const float4*>(q);
    const float4 v1 = *reinterpret_cast<const float4*>(q + 4);
    s[0] += v0.x; s[1] += v0.y; s[2] += v0.z; s[3] += v0.w;
    s[4] += v1.x; s[5] += v1.y; s[6] += v1.z; s[7] += v1.w;
  }
  bf16x8 o;
#pragma unroll
  for (int j = 0; j < 8; ++j) o[j] = (short)f2bf(s[j]);
  *reinterpret_cast<bf16x8*>(hb + i) = o;
}

// ---- aggregation 1 (+b1, relu): edges LDS-staged in 64-chunks ----
__global__ __launch_bounds__(256)
void k_agg1(const unsigned short* __restrict__ hb, const int* __restrict__ rowp,
            const int* __restrict__ cols, const float* __restrict__ nrm,
            const float* __restrict__ dinv, const float* __restrict__ b1,
            float* __restrict__ out1) {
  __shared__ int   scols[64];
  __shared__ float snrm[64];
  const int i = blockIdx.x;
  const int c = threadIdx.x;
  const int beg = rowp[i], end = rowp[i + 1];
  const float di = dinv[i];
  float acc = di * di * bf2f(hb[(size_t)i * CH + c]);
  for (int base = beg; base < end; base += 64) {
    const int m = min(64, end - base);
    __syncthreads();
    if (c < m) { scols[c] = cols[base + c]; snrm[c] = nrm[base + c]; }
    __syncthreads();
    for (int j = 0; j < m; ++j)
      acc += snrm[j] * bf2f(hb[(size_t)scols[j] * CH + c]);
  }
  out1[(size_t)i * CH + c] = fmaxf(acc + b1[c], 0.0f);
}

// ---- GEMM2: h2[16384][16] = out1 @ W2[256][16] ----
__global__ __launch_bounds__(256)
void k_gemm2(const float* __restrict__ out1, const float* __restrict__ w2,
             float* __restrict__ h2) {
  __shared__ float xs[16][256];
  __shared__ float ws[256 * 16];
  const int t = threadIdx.x;
  const int n0 = blockIdx.x * 16;
#pragma unroll
  for (int i = 0; i < 16; ++i) ws[i * 256 + t] = w2[i * 256 + t];
#pragma unroll
  for (int i = 0; i < 16; ++i) xs[i][t] = out1[(size_t)(n0 + i) * CH + t];
  __syncthreads();
  const int node = t >> 4, k = t & 15;
  float acc = 0.f;
#pragma unroll 8
  for (int c = 0; c < 256; ++c) acc += xs[node][c] * ws[c * 16 + k];
  h2[(size_t)(n0 + node) * KC + k] = acc;
}

// ---- aggregation 2 (+b2): one wave per node ----
__global__ __launch_bounds__(256)
void k_agg2(const float* __restrict__ h2, const int* __restrict__ rowp,
            const int* __restrict__ cols, const float* __restrict__ nrm,
            const float* __restrict__ dinv, const float* __restrict__ b2,
            float* __restrict__ out) {
  const int i = blockIdx.x * 4 + (threadIdx.x >> 6);
  const int lane = threadIdx.x & 63;
  const int k = lane & 15, g = lane >> 4;
  const int beg = rowp[i], end = rowp[i + 1];
  float acc = 0.f;
  for (int e = beg + g; e < end; e += 4)
    acc += nrm[e] * h2[(size_t)cols[e] * KC + k];
  acc += __shfl_xor(acc, 16);
  acc += __shfl_xor(acc, 32);
  if (g == 0) {
    const float di = dinv[i];
    out[(size_t)i * KC + k] = acc + di * di * h2[(size_t)i * KC + k] + b2[k];
  }
}

extern "C" void kernel_launch(void* const* d_in, const int* in_sizes, int n_in,
                              void* d_out, int out_size, void* d_ws, size_t ws_size,
                              hipStream_t stream) {
  const float* x  = (const float*)d_in[0];
  const int*   ei = (const int*)d_in[1];
  const float* ew = (const float*)d_in[2];
  const float* w1 = (const float*)d_in[3];
  const float* b1 = (const float*)d_in[4];
  const float* w2 = (const float*)d_in[5];
  const float* b2 = (const float*)d_in[6];
  const int* src = ei;
  const int* dst = ei + NE;

  uint8_t* ws = (uint8_t*)d_ws;
  unsigned short* w1t = (unsigned short*)(ws + OFF_W1T);
  float* hp   = (float*)(ws + OFF_HP);
  unsigned short* hb = (unsigned short*)(ws + OFF_HB);
  float* out1 = (float*)(ws + OFF_OUT1);
  float* h2   = (float*)(ws + OFF_H2);
  float* deg  = (float*)(ws + OFF_DEG);
  int*   cnt  = (int*)(ws + OFF_CNT);
  float* dinv = (float*)(ws + OFF_DINV);
  int*   rowp = (int*)(ws + OFF_ROWP);
  int*   curs = (int*)(ws + OFF_CUR);
  int*   cols = (int*)(ws + OFF_COLS);
  float* nrm  = (float*)(ws + OFF_NRM);
  float* out  = (float*)d_out;

  hipMemsetAsync(ws + OFF_DEG, 0, 131072, stream);  // deg + cnt

  k_w1t <<<dim3(256, 4), 256, 0, stream>>>(w1, w1t);
  k_deg <<<NE / 256, 256, 0, stream>>>(dst, ew, deg, cnt);
  k_dinv<<<NN / 256, 256, 0, stream>>>(deg, dinv);
  k_scan<<<1, 256, 0, stream>>>(cnt, rowp, curs);
  k_fill<<<NE / 256, 256, 0, stream>>>(src, dst, ew, dinv, curs, cols, nrm);
  k_gemm1<<<(NN / BM) * KSPLIT, 256, 0, stream>>>(x, w1t, hp);
  k_hred<<<NN * CH / (256 * 8), 256, 0, stream>>>(hp, hb);
  k_agg1<<<NN, 256, 0, stream>>>(hb, rowp, cols, nrm, dinv, b1, out1);
  k_gemm2<<<NN / 16, 256, 0, stream>>>(out1, w2, h2);
  k_agg2<<<NN / 4, 256, 0, stream>>>(h2, rowp, cols, nrm, dinv, b2, out);
}

// Round 4
// 469.043 us; speedup vs baseline: 1.4622x; 1.0325x over previous
//
#include <hip/hip_runtime.h>
#include <stdint.h>

// GCN 2-layer: h1 = relu(Anorm @ (x@W1) + b1); out = Anorm @ (h1@W2) + b2
// R4: GEMM1 pinned to 2 blocks/CU (__launch_bounds__(256,2)) + setprio around
//     MFMA cluster; agg1 redesigned wave-parallel (4 waves x edge-strided,
//     lane owns 4 channels, LDS cross-wave reduce).

namespace {
constexpr int NN = 16384;     // nodes
constexpr int CH = 256;       // hidden channels
constexpr int KC = 16;        // classes
constexpr int NE = 524288;    // edges
constexpr int KD = 16384;     // input feature dim
constexpr int KSPLIT = 4;
constexpr int BM = 128;

// workspace byte offsets
constexpr size_t OFF_W1T  = 0;            // bf16 [256][16384]        = 8 MiB
constexpr size_t OFF_HP   = 8388608;      // f32  [4][16384][256]     = 64 MiB
constexpr size_t OFF_HB   = 75497472;     // bf16 [16384][256]        = 8 MiB
constexpr size_t OFF_OUT1 = 83886080;     // f32  [16384][256]        = 16 MiB
constexpr size_t OFF_H2   = 100663296;    // f32  [16384][16]         = 1 MiB
constexpr size_t OFF_DEG  = 101711872;    // f32  [16384]
constexpr size_t OFF_CNT  = 101777408;    // i32  [16384] (contiguous w/ DEG)
constexpr size_t OFF_DINV = 101842944;    // f32  [16384]
constexpr size_t OFF_ROWP = 101908480;    // i32  [16385]
constexpr size_t OFF_CUR  = 102039552;    // i32  [16384]
constexpr size_t OFF_COLS = 102105088;    // i32  [E] = 2 MiB
constexpr size_t OFF_NRM  = 104202240;    // f32  [E] = 2 MiB
}

typedef __attribute__((ext_vector_type(8))) short bf16x8;
typedef __attribute__((ext_vector_type(4))) float f32x4;

__device__ __forceinline__ unsigned short f2bf(float f) {
  unsigned int u = __builtin_bit_cast(unsigned int, f);
  u += 0x7fffu + ((u >> 16) & 1u);
  return (unsigned short)(u >> 16);
}
__device__ __forceinline__ float bf2f(unsigned short v) {
  unsigned int u = ((unsigned int)v) << 16;
  return __builtin_bit_cast(float, u);
}

// ---- W1 [16384][256] f32  ->  W1T [256][16384] bf16 ----
__global__ __launch_bounds__(256)
void k_w1t(const float* __restrict__ w1, unsigned short* __restrict__ w1t) {
  __shared__ float tile[64][65];
  const int t = threadIdx.x;
  const int kb = blockIdx.x * 64;
  const int nb = blockIdx.y * 64;
  const int r = t >> 6;
  const int c = t & 63;
#pragma unroll
  for (int i = 0; i < 16; ++i)
    tile[i * 4 + r][c] = w1[(size_t)(kb + i * 4 + r) * CH + nb + c];
  __syncthreads();
#pragma unroll
  for (int i = 0; i < 16; ++i)
    w1t[(size_t)(nb + i * 4 + r) * KD + kb + c] = f2bf(tile[c][i * 4 + r]);
}

// ---- degree + in-edge histogram ----
__global__ __launch_bounds__(256)
void k_deg(const int* __restrict__ dst, const float* __restrict__ ew,
           float* __restrict__ deg, int* __restrict__ cnt) {
  const int e = blockIdx.x * 256 + threadIdx.x;
  const int d = dst[e];
  atomicAdd(&deg[d], ew[e]);
  atomicAdd(&cnt[d], 1);
}

__global__ __launch_bounds__(256)
void k_dinv(const float* __restrict__ deg, float* __restrict__ dinv) {
  const int i = blockIdx.x * 256 + threadIdx.x;
  dinv[i] = rsqrtf(deg[i] + 1.0f);   // +1 = self-loop weight
}

// ---- exclusive scan of cnt[16384] -> rowp, cursor (single block) ----
__global__ __launch_bounds__(256)
void k_scan(const int* __restrict__ cnt, int* __restrict__ rowp, int* __restrict__ curs) {
  __shared__ int ps[256];
  const int t = threadIdx.x;
  const int base = t * 64;
  int s = 0;
  for (int j = 0; j < 64; ++j) s += cnt[base + j];
  ps[t] = s;
  __syncthreads();
  int v = s;
  for (int off = 1; off < 256; off <<= 1) {
    int u = (t >= off) ? ps[t - off] : 0;
    __syncthreads();
    v += u;
    ps[t] = v;
    __syncthreads();
  }
  int run = v - s;
  for (int j = 0; j < 64; ++j) {
    int c = cnt[base + j];
    rowp[base + j] = run;
    curs[base + j] = run;
    run += c;
  }
  if (t == 255) rowp[NN] = run;
}

// ---- CSR fill: edge -> (src, norm) bucketed by dst ----
__global__ __launch_bounds__(256)
void k_fill(const int* __restrict__ src, const int* __restrict__ dst,
            const float* __restrict__ ew, const float* __restrict__ dinv,
            int* __restrict__ curs, int* __restrict__ cols, float* __restrict__ nrm) {
  const int e = blockIdx.x * 256 + threadIdx.x;
  const int s = src[e], d = dst[e];
  const int pos = atomicAdd(&curs[d], 1);
  cols[pos] = s;
  nrm[pos] = dinv[s] * ew[e] * dinv[d];
}

// ---- GEMM1: hp[kb][16384][256] = x[:, kb-quarter] @ W1T[kb-quarter] ----
// BM=128 BN=256 BK=32, KSPLIT=4 -> grid 512. __launch_bounds__(256,2) pins
// VGPR<=256 so 2 blocks/CU co-reside (barrier drains overlap across blocks).
__global__ __launch_bounds__(256, 2)
void k_gemm1(const float* __restrict__ x, const unsigned short* __restrict__ w1t,
             float* __restrict__ hp) {
  __shared__ __align__(16) unsigned short As[2][BM * 32];    // 16 KB
  __shared__ __align__(16) unsigned short Bs[2][256 * 32];   // 32 KB

  const int tid  = threadIdx.x;
  const int lane = tid & 63;
  const int wave = tid >> 6;

  const int bid  = blockIdx.x;
  const int xcd  = bid & 7;
  const int slot = bid >> 3;                   // 0..63
  const int kb   = xcd >> 1;                   // 0..3, constant per XCD
  const int bm0  = (slot * 2 + (xcd & 1)) * BM;
  const int koff = kb * (KD / KSPLIT);         // 4096-col quarter
  const int wn0  = wave * 64;

  // A staging: thread -> rows r0, r0+64, k-chunk kq (8 floats), XOR chunk swz
  const int r0  = tid >> 2;
  const int kq  = tid & 3;
  const int acn = kq ^ ((r0 >> 1) & 3);
  const int aoff0 = r0 * 32 + acn * 8;
  const int aoff1 = (r0 + 64) * 32 + acn * 8;

  // B async staging: linear LDS dest, pre-swizzled global source
  const int cc = (lane & 3) ^ ((lane >> 3) & 3);
  const unsigned short* bbase =
      w1t + (size_t)(wave * 64 + (lane >> 2)) * KD + koff + cc * 8;

  // fragment-read coords
  const int fr = lane & 15, fg = lane >> 4;
  const int fch = fg ^ ((fr >> 1) & 3);
  const int fA = fr * 32 + fch * 8;
  const int fB = (wn0 + fr) * 32 + fch * 8;

  const float* xrow0 = x + (size_t)(bm0 + r0) * KD + koff + kq * 8;
  const float* xrow1 = xrow0 + (size_t)64 * KD;

  float4 a00, a01, a10, a11;
  f32x4 acc[8][4] = {};

  auto GLOADB = [&](int t, int buf) {
    const unsigned short* g = bbase + (size_t)t * 32;
#pragma unroll
    for (int i = 0; i < 4; ++i) {
      __builtin_amdgcn_global_load_lds(
          (const __attribute__((address_space(1))) void*)(g + (size_t)i * 16 * KD),
          (__attribute__((address_space(3))) void*)(&Bs[buf][(wave * 64 + i * 16) * 32]),
          16, 0, 0);
    }
  };
  auto LOADA = [&](int t) {
    const float* p0 = xrow0 + (size_t)t * 32;
    const float* p1 = xrow1 + (size_t)t * 32;
    a00 = *reinterpret_cast<const float4*>(p0);
    a01 = *reinterpret_cast<const float4*>(p0 + 4);
    a10 = *reinterpret_cast<const float4*>(p1);
    a11 = *reinterpret_cast<const float4*>(p1 + 4);
  };
  auto STOREA = [&](int buf) {
    bf16x8 v;
    v[0] = (short)f2bf(a00.x); v[1] = (short)f2bf(a00.y);
    v[2] = (short)f2bf(a00.z); v[3] = (short)f2bf(a00.w);
    v[4] = (short)f2bf(a01.x); v[5] = (short)f2bf(a01.y);
    v[6] = (short)f2bf(a01.z); v[7] = (short)f2bf(a01.w);
    *reinterpret_cast<bf16x8*>(&As[buf][aoff0]) = v;
    v[0] = (short)f2bf(a10.x); v[1] = (short)f2bf(a10.y);
    v[2] = (short)f2bf(a10.z); v[3] = (short)f2bf(a10.w);
    v[4] = (short)f2bf(a11.x); v[5] = (short)f2bf(a11.y);
    v[6] = (short)f2bf(a11.z); v[7] = (short)f2bf(a11.w);
    *reinterpret_cast<bf16x8*>(&As[buf][aoff1]) = v;
  };

  constexpr int NT = KD / KSPLIT / 32;   // 128
  GLOADB(0, 0);
  LOADA(0);
  STOREA(0);
  __syncthreads();
  int cur = 0;

  for (int t = 0; t < NT; ++t) {
    if (t + 1 < NT) {
      GLOADB(t + 1, cur ^ 1);
      LOADA(t + 1);
    }
    bf16x8 bfr[4];
#pragma unroll
    for (int ni = 0; ni < 4; ++ni)
      bfr[ni] = *reinterpret_cast<const bf16x8*>(&Bs[cur][fB + ni * 512]);
    __builtin_amdgcn_s_setprio(1);
#pragma unroll
    for (int mi = 0; mi < 8; ++mi) {
      const bf16x8 af = *reinterpret_cast<const bf16x8*>(&As[cur][fA + mi * 512]);
#pragma unroll
      for (int ni = 0; ni < 4; ++ni)
        acc[mi][ni] = __builtin_amdgcn_mfma_f32_16x16x32_bf16(af, bfr[ni], acc[mi][ni], 0, 0, 0);
    }
    __builtin_amdgcn_s_setprio(0);
    if (t + 1 < NT) {
      STOREA(cur ^ 1);
      __syncthreads();
      cur ^= 1;
    }
  }

  float* hpo = hp + (size_t)kb * NN * CH;
#pragma unroll
  for (int mi = 0; mi < 8; ++mi)
#pragma unroll
    for (int ni = 0; ni < 4; ++ni)
#pragma unroll
      for (int r = 0; r < 4; ++r) {
        const int m = bm0 + mi * 16 + fg * 4 + r;
        const int n = wn0 + ni * 16 + fr;
        hpo[(size_t)m * CH + n] = acc[mi][ni][r];
      }
}

// ---- reduce 4 partials -> h bf16 ----
__global__ __launch_bounds__(256)
void k_hred(const float* __restrict__ hp, unsigned short* __restrict__ hb) {
  const size_t i = ((size_t)blockIdx.x * 256 + threadIdx.x) * 8;
  float s[8];
#pragma unroll
  for (int j = 0; j < 8; ++j) s[j] = 0.f;
#pragma unroll
  for (int p = 0; p < KSPLIT; ++p) {
    const float* q = hp + (size_t)p * NN * CH + i;
    const float4 v0 = *reinterpret_cast<const float4*>(q);
    const float4 v1 = *reinterpret_cast<const float4*>(q + 4);
    s[0] += v0.x; s[1] += v0.y; s[2] += v0.z; s[3] += v0.w;
    s[4] += v1.x; s[5] += v1.y; s[6] += v1.z; s[7] += v1.w;
  }
  bf16x8 o;
#pragma unroll
  for (int j = 0; j < 8; ++j) o[j] = (short)f2bf(s[j]);
  *reinterpret_cast<bf16x8*>(hb + i) = o;
}

// ---- aggregation 1 (+b1, relu): wave-parallel edges, lane owns 4 channels ----
__global__ __launch_bounds__(256)
void k_agg1(const unsigned short* __restrict__ hb, const int* __restrict__ rowp,
            const int* __restrict__ cols, const float* __restrict__ nrm,
            const float* __restrict__ dinv, const float* __restrict__ b1,
            float* __restrict__ out1) {
  __shared__ float red[4][256];
  const int i = blockIdx.x;
  const int t = threadIdx.x;
  const int w = t >> 6, l = t & 63;
  const int beg = rowp[i], end = rowp[i + 1];
  float a0 = 0.f, a1 = 0.f, a2 = 0.f, a3 = 0.f;
  int e = beg + w;
  // 2-deep unroll: two edges in flight per wave
  for (; e + 4 < end; e += 8) {
    const int s0 = cols[e], s1 = cols[e + 4];
    const float n0 = nrm[e], n1 = nrm[e + 4];
    const ushort4 h0 = *reinterpret_cast<const ushort4*>(hb + (size_t)s0 * CH + l * 4);
    const ushort4 h1 = *reinterpret_cast<const ushort4*>(hb + (size_t)s1 * CH + l * 4);
    a0 += n0 * bf2f(h0.x) + n1 * bf2f(h1.x);
    a1 += n0 * bf2f(h0.y) + n1 * bf2f(h1.y);
    a2 += n0 * bf2f(h0.z) + n1 * bf2f(h1.z);
    a3 += n0 * bf2f(h0.w) + n1 * bf2f(h1.w);
  }
  if (e < end) {
    const int s0 = cols[e];
    const float n0 = nrm[e];
    const ushort4 h0 = *reinterpret_cast<const ushort4*>(hb + (size_t)s0 * CH + l * 4);
    a0 += n0 * bf2f(h0.x); a1 += n0 * bf2f(h0.y);
    a2 += n0 * bf2f(h0.z); a3 += n0 * bf2f(h0.w);
  }
  *reinterpret_cast<float4*>(&red[w][l * 4]) = make_float4(a0, a1, a2, a3);
  __syncthreads();
  // thread t finalizes channel t
  const float di = dinv[i];
  float sum = red[0][t] + red[1][t] + red[2][t] + red[3][t]
            + di * di * bf2f(hb[(size_t)i * CH + t]) + b1[t];
  out1[(size_t)i * CH + t] = fmaxf(sum, 0.0f);
}

// ---- GEMM2: h2[16384][16] = out1 @ W2[256][16] ----
__global__ __launch_bounds__(256)
void k_gemm2(const float* __restrict__ out1, const float* __restrict__ w2,
             float* __restrict__ h2) {
  __shared__ float xs[16][256];
  __shared__ float ws[256 * 16];
  const int t = threadIdx.x;
  const int n0 = blockIdx.x * 16;
#pragma unroll
  for (int i = 0; i < 16; ++i) ws[i * 256 + t] = w2[i * 256 + t];
#pragma unroll
  for (int i = 0; i < 16; ++i) xs[i][t] = out1[(size_t)(n0 + i) * CH + t];
  __syncthreads();
  const int node = t >> 4, k = t & 15;
  float acc = 0.f;
#pragma unroll 8
  for (int c = 0; c < 256; ++c) acc += xs[node][c] * ws[c * 16 + k];
  h2[(size_t)(n0 + node) * KC + k] = acc;
}

// ---- aggregation 2 (+b2): one wave per node ----
__global__ __launch_bounds__(256)
void k_agg2(const float* __restrict__ h2, const int* __restrict__ rowp,
            const int* __restrict__ cols, const float* __restrict__ nrm,
            const float* __restrict__ dinv, const float* __restrict__ b2,
            float* __restrict__ out) {
  const int i = blockIdx.x * 4 + (threadIdx.x >> 6);
  const int lane = threadIdx.x & 63;
  const int k = lane & 15, g = lane >> 4;
  const int beg = rowp[i], end = rowp[i + 1];
  float acc = 0.f;
  for (int e = beg + g; e < end; e += 4)
    acc += nrm[e] * h2[(size_t)cols[e] * KC + k];
  acc += __shfl_xor(acc, 16);
  acc += __shfl_xor(acc, 32);
  if (g == 0) {
    const float di = dinv[i];
    out[(size_t)i * KC + k] = acc + di * di * h2[(size_t)i * KC + k] + b2[k];
  }
}

extern "C" void kernel_launch(void* const* d_in, const int* in_sizes, int n_in,
                              void* d_out, int out_size, void* d_ws, size_t ws_size,
                              hipStream_t stream) {
  const float* x  = (const float*)d_in[0];
  const int*   ei = (const int*)d_in[1];
  const float* ew = (const float*)d_in[2];
  const float* w1 = (const float*)d_in[3];
  const float* b1 = (const float*)d_in[4];
  const float* w2 = (const float*)d_in[5];
  const float* b2 = (const float*)d_in[6];
  const int* src = ei;
  const int* dst = ei + NE;

  uint8_t* ws = (uint8_t*)d_ws;
  unsigned short* w1t = (unsigned short*)(ws + OFF_W1T);
  float* hp   = (float*)(ws + OFF_HP);
  unsigned short* hb = (unsigned short*)(ws + OFF_HB);
  float* out1 = (float*)(ws + OFF_OUT1);
  float* h2   = (float*)(ws + OFF_H2);
  float* deg  = (float*)(ws + OFF_DEG);
  int*   cnt  = (int*)(ws + OFF_CNT);
  float* dinv = (float*)(ws + OFF_DINV);
  int*   rowp = (int*)(ws + OFF_ROWP);
  int*   curs = (int*)(ws + OFF_CUR);
  int*   cols = (int*)(ws + OFF_COLS);
  float* nrm  = (float*)(ws + OFF_NRM);
  float* out  = (float*)d_out;

  hipMemsetAsync(ws + OFF_DEG, 0, 131072, stream);  // deg + cnt

  k_w1t <<<dim3(256, 4), 256, 0, stream>>>(w1, w1t);
  k_deg <<<NE / 256, 256, 0, stream>>>(dst, ew, deg, cnt);
  k_dinv<<<NN / 256, 256, 0, stream>>>(deg, dinv);
  k_scan<<<1, 256, 0, stream>>>(cnt, rowp, curs);
  k_fill<<<NE / 256, 256, 0, stream>>>(src, dst, ew, dinv, curs, cols, nrm);
  k_gemm1<<<(NN / BM) * KSPLIT, 256, 0, stream>>>(x, w1t, hp);
  k_hred<<<NN * CH / (256 * 8), 256, 0, stream>>>(hp, hb);
  k_agg1<<<NN, 256, 0, stream>>>(hb, rowp, cols, nrm, dinv, b1, out1);
  k_gemm2<<<NN / 16, 256, 0, stream>>>(out1, w2, h2);
  k_agg2<<<NN / 4, 256, 0, stream>>>(h2, rowp, cols, nrm, dinv, b2, out);
}